// Round 1
// baseline (43.796 us; speedup 1.0000x reference)
//
#include <hip/hip_runtime.h>

// ScaledRBFKernel: out[i][j] = outputscale * exp(-2 * ||x1[i] - x2[j]||^2)
// x1: [8192,2] f32, x2: [8192,2] f32, out: [8192,8192] f32 (256 MB -> write-BW bound)
// LENGTHSCALE = 0.5 -> 1/(2*l^2) = 2.0 (compile-time constant)

#define N_ROWS 8192
#define M_COLS 8192

__global__ __launch_bounds__(256) void ScaledRBFKernel_55052890800187_kernel(
    const float2* __restrict__ x1,   // [N,2] viewed as float2
    const float2* __restrict__ x2,   // [M,2] viewed as float2
    const float* __restrict__ oscale,
    float* __restrict__ out)
{
    const int i  = blockIdx.y;                              // row 0..8191
    const int j4 = blockIdx.x * blockDim.x + threadIdx.x;   // col-group of 4: 0..2047

    const float2 a = x1[i];          // broadcast within the block (L1 hit)
    const float  s = oscale[0];

    // 4 consecutive x2 points = 32 B/lane, coalesced across lanes
    const float4* x2v = reinterpret_cast<const float4*>(x2);
    float4 p0 = x2v[j4 * 2 + 0];     // (x2[4j].x, x2[4j].y, x2[4j+1].x, x2[4j+1].y)
    float4 p1 = x2v[j4 * 2 + 1];     // (x2[4j+2].x, ..., x2[4j+3].y)

    float4 r;
    {
        float dx = a.x - p0.x, dy = a.y - p0.y;
        r.x = s * __expf(-2.0f * (dx * dx + dy * dy));
    }
    {
        float dx = a.x - p0.z, dy = a.y - p0.w;
        r.y = s * __expf(-2.0f * (dx * dx + dy * dy));
    }
    {
        float dx = a.x - p1.x, dy = a.y - p1.y;
        r.z = s * __expf(-2.0f * (dx * dx + dy * dy));
    }
    {
        float dx = a.x - p1.z, dy = a.y - p1.w;
        r.w = s * __expf(-2.0f * (dx * dx + dy * dy));
    }

    reinterpret_cast<float4*>(out)[(size_t)i * (M_COLS / 4) + j4] = r;
}

extern "C" void kernel_launch(void* const* d_in, const int* in_sizes, int n_in,
                              void* d_out, int out_size, void* d_ws, size_t ws_size,
                              hipStream_t stream)
{
    const float2* x1 = (const float2*)d_in[0];
    const float2* x2 = (const float2*)d_in[1];
    const float*  os = (const float*)d_in[2];
    float* out = (float*)d_out;

    // grid: x covers 8192/4 = 2048 col-groups with 256-thread blocks -> 8 blocks;
    //       y covers 8192 rows. 65536 blocks total.
    dim3 block(256, 1, 1);
    dim3 grid((M_COLS / 4) / 256, N_ROWS, 1);
    ScaledRBFKernel_55052890800187_kernel<<<grid, block, 0, stream>>>(x1, x2, os, out);
}